// Round 8
// baseline (288.198 us; speedup 1.0000x reference)
//
#include <hip/hip_runtime.h>
#include <hip/hip_bf16.h>

typedef __bf16 bf16x8 __attribute__((ext_vector_type(8)));
typedef __bf16 bf16x4 __attribute__((ext_vector_type(4)));
typedef float floatx4 __attribute__((ext_vector_type(4)));

// Async global->LDS DMA, 16 B per lane. Dest is wave-uniform base + lane*16.
__device__ __forceinline__ void async16(void* lds, const void* g) {
  __builtin_amdgcn_global_load_lds(
      (const __attribute__((address_space(1))) unsigned int*)g,
      (__attribute__((address_space(3))) unsigned int*)lds, 16, 0, 0);
}

// Fused preprocess: x->bf16 (blocks 0..2047), K->bf16 (2048..3071),
// V->Vt bf16 transpose (3072..4095), lsum zero (4096), out zero (4097..6144,
// needed because GEMM2 is K-split and accumulates with atomicAdd).
__global__ __launch_bounds__(256) void preprocess_kernel(
    const float* __restrict__ x, const float* __restrict__ Kp,
    const float* __restrict__ V, __bf16* __restrict__ xb,
    __bf16* __restrict__ Kb, __bf16* __restrict__ Vt,
    float* __restrict__ lsum, float* __restrict__ outz) {
  const int b = blockIdx.x;
  const int t = threadIdx.x;
  if (b < 2048) {
#pragma unroll
    for (int k = 0; k < 2; ++k) {
      const int i8 = b * 512 + k * 256 + t;
      float4 va = ((const float4*)x)[2 * i8];
      float4 vb = ((const float4*)x)[2 * i8 + 1];
      bf16x8 o = {(__bf16)va.x, (__bf16)va.y, (__bf16)va.z, (__bf16)va.w,
                  (__bf16)vb.x, (__bf16)vb.y, (__bf16)vb.z, (__bf16)vb.w};
      ((bf16x8*)xb)[i8] = o;
    }
  } else if (b < 3072) {
#pragma unroll
    for (int k = 0; k < 2; ++k) {
      const int i8 = (b - 2048) * 512 + k * 256 + t;
      float4 va = ((const float4*)Kp)[2 * i8];
      float4 vb = ((const float4*)Kp)[2 * i8 + 1];
      bf16x8 o = {(__bf16)va.x, (__bf16)va.y, (__bf16)va.z, (__bf16)va.w,
                  (__bf16)vb.x, (__bf16)vb.y, (__bf16)vb.z, (__bf16)vb.w};
      ((bf16x8*)Kb)[i8] = o;
    }
  } else if (b < 4096) {
    __shared__ float tile[64][65];
    const int bb = b - 3072;
    const int bx = bb & 63, by = bb >> 6;
#pragma unroll
    for (int k = 0; k < 4; ++k) {
      const int i = k * 256 + t;
      const int r = i >> 4, c4 = (i & 15) << 2;
      float4 v = *(const float4*)&V[(size_t)(bx * 64 + r) * 1024 + by * 64 + c4];
      tile[r][c4] = v.x; tile[r][c4 + 1] = v.y;
      tile[r][c4 + 2] = v.z; tile[r][c4 + 3] = v.w;
    }
    __syncthreads();
#pragma unroll
    for (int k = 0; k < 2; ++k) {
      const int i = k * 256 + t;
      const int e = i >> 3, sg = (i & 7) << 3;
      bf16x8 o;
#pragma unroll
      for (int j = 0; j < 8; ++j) o[j] = (__bf16)tile[sg + j][e];
      *(bf16x8*)&Vt[(size_t)(by * 64 + e) * 4096 + bx * 64 + sg] = o;
    }
  } else if (b == 4096) {
#pragma unroll
    for (int k = 0; k < 8; ++k)
      ((floatx4*)lsum)[k * 256 + t] = floatx4{0.f, 0.f, 0.f, 0.f};
  } else {
    const size_t bb = b - 4097;
#pragma unroll
    for (int k = 0; k < 4; ++k)
      ((float4*)outz)[bb * 1024 + k * 256 + t] = float4{0.f, 0.f, 0.f, 0.f};
  }
}

// C = A (M x K bf16, row stride LD) x B (N rows of K bf16, row stride LD).
// BM=BN=256, BK=64. 512 threads = 8 waves (2M x 4N), wave-tile 128x64,
// acc[8][4]. m201-style 4-phase/K-tile schedule (identical to round 3).
// ROUND-8 FIX: __launch_bounds__(512, 1). R3/R4's (512, 2) squeezed the
// allocator to a 128-VGPR budget (4 waves/EU) -- but acc[8][4] alone is 128
// VGPRs, so the accumulator spilled to scratch (VGPR_Count=128 observed),
// explaining the 2.4x-slower-than-template K-tile time with low MfmaUtil AND
// low VALUBusy. With min-waves=1 the cap is 512; ~250 VGPRs fits the LDS-pinned
// occupancy (1 block/CU = 2 waves/SIMD) with zero spill.
//   phase = (i-half, k-slice): q0=(i0-3,ks0) q1=(i4-7,ks0) q2=(i0-3,ks1) q3=(i4-7,ks1)
//   each phase: {ds_read 4-8 x b128 || stage ONE k-half (2 x global_load_lds)}
//               -> s_barrier -> lgkmcnt(0)+sched_barrier -> setprio(1) 16 MFMA
//               setprio(0) -> s_barrier.
// LDS 128 KiB = 2 bufs x {A kh0, A kh1, B kh0, B kh1} x 16 KiB; stage ring:
//   q0(T)->A-kh1(T+1), q1(T)->B-kh1(T+1), q2(T)->A-kh0(T+2), q3(T)->B-kh0(T+2)
// vmcnt(8) before the q1/q3 barriers; never vmcnt(0) except the last tile.
// Swizzle: element (row m, k-chunk q of the 32-k half) at byte
// (m>>1)*128 + ((((m&1)*4+q) ^ ((m>>1)&7))*16); LDS dest linear (t*16),
// global source pre-swizzled (verified conflict-free: SQ_LDS_BANK_CONFLICT=0).
// Grid: mt-fastest within XCD; SPL = K-split slices.
// MODE 0: P = exp(min(dot/32,30)) -> bf16 Cb + fused row-sum atomicAdd.
// MODE 1: atomicAdd(out, dot/lsum[m]) (K-split partial; linear in 1/lsum).
template <int MODE, int LD, int KR, int NS, int MTX, int SPL>
__global__ __launch_bounds__(512, 1) void gemm_kernel(const __bf16* __restrict__ A,
                                                      const __bf16* __restrict__ B,
                                                      __bf16* __restrict__ Cb,
                                                      float* __restrict__ Cf,
                                                      float* __restrict__ lsum) {
  constexpr int NT = KR / 64;
  __shared__ char lds[131072];

  const int t = threadIdx.x;
  const int lane = t & 63;
  const int w = t >> 6;
  const int wm = w >> 2;  // 0..1 (A 128-row band)
  const int wn = w & 3;   // 0..3 (B 64-row band)

  const int id = blockIdx.x;
  const int g = id & 7;
  const int s = id >> 3;
  const int ks = s % SPL;
  const int r2 = s / SPL;
  const int mt = g * MTX + (r2 % MTX);
  const int nt = r2 / MTX;
  const int m0 = mt * 256;
  const int n0 = nt * 256;
  const size_t koff = (size_t)ks * KR;

  // staging source map (pre-swizzled global, linear LDS dest)
  const int v = (t & 7) ^ ((t >> 3) & 7);
  const int srow = 2 * (t >> 3) + (v >> 2);
  const int sk8 = (v & 3) * 8;
  const __bf16* aS = A + (size_t)(m0 + srow) * LD + koff + sk8;
  const __bf16* bS = B + (size_t)(n0 + srow) * LD + koff + sk8;
  const int t16 = t * 16;

  auto stageA = [&](int slot, int kElem) {
    const __bf16* p = aS + kElem;
    async16(lds + slot + t16, p);
    async16(lds + slot + 8192 + t16, p + (size_t)128 * LD);
  };
  auto stageB = [&](int slot, int kElem) {
    const __bf16* p = bS + kElem;
    async16(lds + slot + t16, p);
    async16(lds + slot + 8192 + t16, p + (size_t)128 * LD);
  };

  // fragment read offset
  const int rl = lane & 15;
  const int qq = lane >> 4;
  const int fo = (rl >> 1) * 128 + (((((rl & 1) << 2) | qq) ^ (rl >> 1)) << 4);
  const int aOff = wm * 8192 + fo;  // + i*1024 within a 16 KiB A k-half slot
  const int bOff = wn * 4096 + fo;  // + j*1024 within a 16 KiB B k-half slot

  floatx4 acc[8][4] = {};

  // LDS slots: buf b (b*65536): A-kh0 +0, A-kh1 +16384, B-kh0 +32768, B-kh1 +49152
  stageA(0, 0);          stageB(32768, 0);
  stageA(16384, 32);     stageB(49152, 32);
  stageA(65536, 64);     stageB(98304, 64);
  asm volatile("s_waitcnt vmcnt(8)" ::: "memory");
  __builtin_amdgcn_s_barrier();

  for (int T = 0; T < NT; ++T) {
    const int bas = (T & 1) << 16;
    const int oth = bas ^ 65536;
    const int kT = T * 64;
    bf16x8 aF[4], bF[4];

    // ---- q0: ks0, i-half0 ----
#pragma unroll
    for (int i = 0; i < 4; ++i) aF[i] = *(const bf16x8*)(lds + bas + aOff + i * 1024);
#pragma unroll
    for (int j = 0; j < 4; ++j) bF[j] = *(const bf16x8*)(lds + bas + 32768 + bOff + j * 1024);
    if (T + 1 < NT) stageA(oth + 16384, kT + 96);  // A-kh1(T+1)
    __builtin_amdgcn_s_barrier();
    asm volatile("s_waitcnt lgkmcnt(0)" ::: "memory");
    __builtin_amdgcn_sched_barrier(0);
    __builtin_amdgcn_s_setprio(1);
#pragma unroll
    for (int i = 0; i < 4; ++i)
#pragma unroll
      for (int j = 0; j < 4; ++j)
        acc[i][j] = __builtin_amdgcn_mfma_f32_16x16x32_bf16(aF[i], bF[j], acc[i][j], 0, 0, 0);
    __builtin_amdgcn_s_setprio(0);
    __builtin_amdgcn_s_barrier();

    // ---- q1: ks0, i-half1 ----
#pragma unroll
    for (int i = 0; i < 4; ++i) aF[i] = *(const bf16x8*)(lds + bas + aOff + 4096 + i * 1024);
    if (T + 1 < NT) stageB(oth + 49152, kT + 96);  // B-kh1(T+1)
    if (T == NT - 1) asm volatile("s_waitcnt vmcnt(0)" ::: "memory");
    else             asm volatile("s_waitcnt vmcnt(8)" ::: "memory");
    __builtin_amdgcn_s_barrier();
    asm volatile("s_waitcnt lgkmcnt(0)" ::: "memory");
    __builtin_amdgcn_sched_barrier(0);
    __builtin_amdgcn_s_setprio(1);
#pragma unroll
    for (int i = 0; i < 4; ++i)
#pragma unroll
      for (int j = 0; j < 4; ++j)
        acc[4 + i][j] = __builtin_amdgcn_mfma_f32_16x16x32_bf16(aF[i], bF[j], acc[4 + i][j], 0, 0, 0);
    __builtin_amdgcn_s_setprio(0);
    __builtin_amdgcn_s_barrier();

    // ---- q2: ks1, i-half0 ----
#pragma unroll
    for (int i = 0; i < 4; ++i) aF[i] = *(const bf16x8*)(lds + bas + 16384 + aOff + i * 1024);
#pragma unroll
    for (int j = 0; j < 4; ++j) bF[j] = *(const bf16x8*)(lds + bas + 49152 + bOff + j * 1024);
    if (T + 2 < NT) stageA(bas, kT + 128);  // A-kh0(T+2)
    __builtin_amdgcn_s_barrier();
    asm volatile("s_waitcnt lgkmcnt(0)" ::: "memory");
    __builtin_amdgcn_sched_barrier(0);
    __builtin_amdgcn_s_setprio(1);
#pragma unroll
    for (int i = 0; i < 4; ++i)
#pragma unroll
      for (int j = 0; j < 4; ++j)
        acc[i][j] = __builtin_amdgcn_mfma_f32_16x16x32_bf16(aF[i], bF[j], acc[i][j], 0, 0, 0);
    __builtin_amdgcn_s_setprio(0);
    __builtin_amdgcn_s_barrier();

    // ---- q3: ks1, i-half1 ----
#pragma unroll
    for (int i = 0; i < 4; ++i) aF[i] = *(const bf16x8*)(lds + bas + 16384 + aOff + 4096 + i * 1024);
    if (T + 2 < NT) stageB(bas + 32768, kT + 128);  // B-kh0(T+2)
    if (T + 2 < NT)      asm volatile("s_waitcnt vmcnt(8)" ::: "memory");
    else if (T + 1 < NT) asm volatile("s_waitcnt vmcnt(4)" ::: "memory");
    __builtin_amdgcn_s_barrier();
    asm volatile("s_waitcnt lgkmcnt(0)" ::: "memory");
    __builtin_amdgcn_sched_barrier(0);
    __builtin_amdgcn_s_setprio(1);
#pragma unroll
    for (int i = 0; i < 4; ++i)
#pragma unroll
      for (int j = 0; j < 4; ++j)
        acc[4 + i][j] = __builtin_amdgcn_mfma_f32_16x16x32_bf16(aF[i], bF[j], acc[4 + i][j], 0, 0, 0);
    __builtin_amdgcn_s_setprio(0);
    __builtin_amdgcn_s_barrier();
  }

  // C/D layout: col = lane&15 (N), row = (lane>>4)*4 + reg (M within 16)
  const int cmB = wm * 128 + ((lane >> 4) << 2);
  const int cn = n0 + wn * 64 + (lane & 15);
  if (MODE == 0) {
#pragma unroll
    for (int i = 0; i < 8; ++i)
#pragma unroll
      for (int r = 0; r < 4; ++r) {
        const int m = m0 + cmB + i * 16 + r;
        float rs = 0.f;
#pragma unroll
        for (int j = 0; j < 4; ++j) {
          const float e = __expf(fminf(acc[i][j][r] * 0.03125f, 30.0f));
          rs += e;
          Cb[(size_t)m * NS + cn + j * 16] = (__bf16)e;
        }
        rs += __shfl_xor(rs, 1, 64);
        rs += __shfl_xor(rs, 2, 64);
        rs += __shfl_xor(rs, 4, 64);
        rs += __shfl_xor(rs, 8, 64);
        if ((lane & 15) == 0) atomicAdd(&lsum[m], rs);
      }
  } else {
#pragma unroll
    for (int i = 0; i < 8; ++i)
#pragma unroll
      for (int r = 0; r < 4; ++r) {
        const int m = m0 + cmB + i * 16 + r;
        const float inv = 1.0f / lsum[m];
#pragma unroll
        for (int j = 0; j < 4; ++j)
          atomicAdd(&Cf[(size_t)m * NS + cn + j * 16], acc[i][j][r] * inv);
      }
  }
}

extern "C" void kernel_launch(void* const* d_in, const int* in_sizes, int n_in,
                              void* d_out, int out_size, void* d_ws, size_t ws_size,
                              hipStream_t stream) {
  const float* x = (const float*)d_in[0];  // [8192][1024] fp32
  const float* K = (const float*)d_in[1];  // [4096][1024] fp32
  const float* V = (const float*)d_in[2];  // [4096][1024] fp32
  float* out = (float*)d_out;              // [8192][1024] fp32

  char* ws = (char*)d_ws;
  __bf16* xb = (__bf16*)ws;                        // 16 MiB
  __bf16* Kb = (__bf16*)(ws + (16u << 20));        // 8 MiB
  __bf16* Vt = (__bf16*)(ws + (24u << 20));        // 8 MiB
  __bf16* P  = (__bf16*)(ws + (32u << 20));        // 64 MiB
  float*  l  = (float*)(ws + (96u << 20));         // 32 KiB

  preprocess_kernel<<<6145, 256, 0, stream>>>(x, K, V, xb, Kb, Vt, l, out);
  // P = exp(xb @ Kb^T / 32), fused row sums (M=8192 N=4096 K=1024), 512 blocks
  gemm_kernel<0, 1024, 1024, 4096, 4, 1><<<512, 512, 0, stream>>>(xb, Kb, P, nullptr, l);
  // out += (P @ Vt-rows)/l, K-split=2 (M=8192 N=1024 K=2x2048), 256 blocks
  gemm_kernel<1, 4096, 2048, 1024, 4, 2><<<256, 512, 0, stream>>>(P, Vt, nullptr, out, l);
}

// Round 9
// 284.267 us; speedup vs baseline: 1.0138x; 1.0138x over previous
//
#include <hip/hip_runtime.h>
#include <hip/hip_bf16.h>

typedef __bf16 bf16x8 __attribute__((ext_vector_type(8)));
typedef __bf16 bf16x4 __attribute__((ext_vector_type(4)));
typedef float floatx4 __attribute__((ext_vector_type(4)));

// Async global->LDS DMA, 16 B per lane. Dest is wave-uniform base + lane*16.
__device__ __forceinline__ void async16(void* lds, const void* g) {
  __builtin_amdgcn_global_load_lds(
      (const __attribute__((address_space(1))) unsigned int*)g,
      (__attribute__((address_space(3))) unsigned int*)lds, 16, 0, 0);
}

// Fused preprocess: x->bf16 (blocks 0..2047), K->bf16 (2048..3071),
// V->Vt bf16 transpose (3072..4095), lsum zero (4096), out zero (4097..6144,
// needed because GEMM2 is K-split and accumulates with atomicAdd).
__global__ __launch_bounds__(256) void preprocess_kernel(
    const float* __restrict__ x, const float* __restrict__ Kp,
    const float* __restrict__ V, __bf16* __restrict__ xb,
    __bf16* __restrict__ Kb, __bf16* __restrict__ Vt,
    float* __restrict__ lsum, float* __restrict__ outz) {
  const int b = blockIdx.x;
  const int t = threadIdx.x;
  if (b < 2048) {
#pragma unroll
    for (int k = 0; k < 2; ++k) {
      const int i8 = b * 512 + k * 256 + t;
      float4 va = ((const float4*)x)[2 * i8];
      float4 vb = ((const float4*)x)[2 * i8 + 1];
      bf16x8 o = {(__bf16)va.x, (__bf16)va.y, (__bf16)va.z, (__bf16)va.w,
                  (__bf16)vb.x, (__bf16)vb.y, (__bf16)vb.z, (__bf16)vb.w};
      ((bf16x8*)xb)[i8] = o;
    }
  } else if (b < 3072) {
#pragma unroll
    for (int k = 0; k < 2; ++k) {
      const int i8 = (b - 2048) * 512 + k * 256 + t;
      float4 va = ((const float4*)Kp)[2 * i8];
      float4 vb = ((const float4*)Kp)[2 * i8 + 1];
      bf16x8 o = {(__bf16)va.x, (__bf16)va.y, (__bf16)va.z, (__bf16)va.w,
                  (__bf16)vb.x, (__bf16)vb.y, (__bf16)vb.z, (__bf16)vb.w};
      ((bf16x8*)Kb)[i8] = o;
    }
  } else if (b < 4096) {
    __shared__ float tile[64][65];
    const int bb = b - 3072;
    const int bx = bb & 63, by = bb >> 6;
#pragma unroll
    for (int k = 0; k < 4; ++k) {
      const int i = k * 256 + t;
      const int r = i >> 4, c4 = (i & 15) << 2;
      float4 v = *(const float4*)&V[(size_t)(bx * 64 + r) * 1024 + by * 64 + c4];
      tile[r][c4] = v.x; tile[r][c4 + 1] = v.y;
      tile[r][c4 + 2] = v.z; tile[r][c4 + 3] = v.w;
    }
    __syncthreads();
#pragma unroll
    for (int k = 0; k < 2; ++k) {
      const int i = k * 256 + t;
      const int e = i >> 3, sg = (i & 7) << 3;
      bf16x8 o;
#pragma unroll
      for (int j = 0; j < 8; ++j) o[j] = (__bf16)tile[sg + j][e];
      *(bf16x8*)&Vt[(size_t)(by * 64 + e) * 4096 + bx * 64 + sg] = o;
    }
  } else if (b == 4096) {
#pragma unroll
    for (int k = 0; k < 8; ++k)
      ((floatx4*)lsum)[k * 256 + t] = floatx4{0.f, 0.f, 0.f, 0.f};
  } else {
    const size_t bb = b - 4097;
#pragma unroll
    for (int k = 0; k < 4; ++k)
      ((float4*)outz)[bb * 1024 + k * 256 + t] = float4{0.f, 0.f, 0.f, 0.f};
  }
}

// C = A (M x K bf16, row stride LD) x B (N rows of K bf16, row stride LD).
// BM=BN=256, BK=64. 512 threads = 8 waves (2M x 4N), wave-tile 128x64,
// acc[8][4] (lives in AGPRs; VGPR_Count=128 arch + 128 acc = 256 total).
// ROUND-9 A/B vs round 8: DELETE the per-phase `asm lgkmcnt(0)` +
// `sched_barrier(0)` pin. Root cause of the 1990-cyc phases (R3/R4/R8):
// sched_barrier(0) pinned all 16 MFMAs behind a FULL LDS drain, serializing
// ~500 cyc of ds_read service with the 515-cyc MFMA cluster. With plain C++
// ds_reads the compiler emits counted per-dependency lgkmcnt, so the first
// MFMAs start as soon as their own operands land and later reads stream in
// under the MFMA cluster (rule-18 hoisting is exactly what the m201 template
// relies on). Phase structure otherwise identical:
//   phase q: {ds_read 4-8 x b128 || stage ONE k-half (2 x global_load_lds)}
//            -> [vmcnt(8) at q1/q3] -> s_barrier -> setprio(1) 16 MFMA
//            setprio(0) -> s_barrier.
// Hazard audit: every frag read feeds an MFMA before the closing barrier
// (lgkm data-drained there); slot overwrite is >=2 barriers later; vmcnt
// guards per-wave, cross-wave completion via vmcnt-before-barrier.
// LDS 128 KiB = 2 bufs x {A kh0, A kh1, B kh0, B kh1} x 16 KiB; stage ring:
//   q0(T)->A-kh1(T+1), q1(T)->B-kh1(T+1), q2(T)->A-kh0(T+2), q3(T)->B-kh0(T+2)
// vmcnt(8) at q1/q3 (4 halves = 8 loads in flight); never vmcnt(0) except the
// last tile (tail: 8 -> 4 -> 0).
// Swizzle: element (row m, k-chunk q of the 32-k half) at byte
// (m>>1)*128 + ((((m&1)*4+q) ^ ((m>>1)&7))*16); LDS dest linear (t*16),
// global source pre-swizzled (verified conflict-free: SQ_LDS_BANK_CONFLICT=0).
// Grid: mt-fastest within XCD; SPL = K-split slices.
// MODE 0: P = exp(min(dot/32,30)) -> bf16 Cb + fused row-sum atomicAdd.
// MODE 1: atomicAdd(out, dot/lsum[m]) (K-split partial; linear in 1/lsum).
template <int MODE, int LD, int KR, int NS, int MTX, int SPL>
__global__ __launch_bounds__(512, 1) void gemm_kernel(const __bf16* __restrict__ A,
                                                      const __bf16* __restrict__ B,
                                                      __bf16* __restrict__ Cb,
                                                      float* __restrict__ Cf,
                                                      float* __restrict__ lsum) {
  constexpr int NT = KR / 64;
  __shared__ char lds[131072];

  const int t = threadIdx.x;
  const int lane = t & 63;
  const int w = t >> 6;
  const int wm = w >> 2;  // 0..1 (A 128-row band)
  const int wn = w & 3;   // 0..3 (B 64-row band)

  const int id = blockIdx.x;
  const int g = id & 7;
  const int s = id >> 3;
  const int ks = s % SPL;
  const int r2 = s / SPL;
  const int mt = g * MTX + (r2 % MTX);
  const int nt = r2 / MTX;
  const int m0 = mt * 256;
  const int n0 = nt * 256;
  const size_t koff = (size_t)ks * KR;

  // staging source map (pre-swizzled global, linear LDS dest)
  const int v = (t & 7) ^ ((t >> 3) & 7);
  const int srow = 2 * (t >> 3) + (v >> 2);
  const int sk8 = (v & 3) * 8;
  const __bf16* aS = A + (size_t)(m0 + srow) * LD + koff + sk8;
  const __bf16* bS = B + (size_t)(n0 + srow) * LD + koff + sk8;
  const int t16 = t * 16;

  auto stageA = [&](int slot, int kElem) {
    const __bf16* p = aS + kElem;
    async16(lds + slot + t16, p);
    async16(lds + slot + 8192 + t16, p + (size_t)128 * LD);
  };
  auto stageB = [&](int slot, int kElem) {
    const __bf16* p = bS + kElem;
    async16(lds + slot + t16, p);
    async16(lds + slot + 8192 + t16, p + (size_t)128 * LD);
  };

  // fragment read offset
  const int rl = lane & 15;
  const int qq = lane >> 4;
  const int fo = (rl >> 1) * 128 + (((((rl & 1) << 2) | qq) ^ (rl >> 1)) << 4);
  const int aOff = wm * 8192 + fo;  // + i*1024 within a 16 KiB A k-half slot
  const int bOff = wn * 4096 + fo;  // + j*1024 within a 16 KiB B k-half slot

  floatx4 acc[8][4] = {};

  // LDS slots: buf b (b*65536): A-kh0 +0, A-kh1 +16384, B-kh0 +32768, B-kh1 +49152
  stageA(0, 0);          stageB(32768, 0);
  stageA(16384, 32);     stageB(49152, 32);
  stageA(65536, 64);     stageB(98304, 64);
  asm volatile("s_waitcnt vmcnt(8)" ::: "memory");
  __builtin_amdgcn_s_barrier();

  for (int T = 0; T < NT; ++T) {
    const int bas = (T & 1) << 16;
    const int oth = bas ^ 65536;
    const int kT = T * 64;
    bf16x8 aF[4], bF[4];

    // ---- q0: ks0, i-half0 ----
#pragma unroll
    for (int i = 0; i < 4; ++i) aF[i] = *(const bf16x8*)(lds + bas + aOff + i * 1024);
#pragma unroll
    for (int j = 0; j < 4; ++j) bF[j] = *(const bf16x8*)(lds + bas + 32768 + bOff + j * 1024);
    if (T + 1 < NT) stageA(oth + 16384, kT + 96);  // A-kh1(T+1)
    __builtin_amdgcn_s_barrier();
    __builtin_amdgcn_s_setprio(1);
#pragma unroll
    for (int i = 0; i < 4; ++i)
#pragma unroll
      for (int j = 0; j < 4; ++j)
        acc[i][j] = __builtin_amdgcn_mfma_f32_16x16x32_bf16(aF[i], bF[j], acc[i][j], 0, 0, 0);
    __builtin_amdgcn_s_setprio(0);
    __builtin_amdgcn_s_barrier();

    // ---- q1: ks0, i-half1 ----
#pragma unroll
    for (int i = 0; i < 4; ++i) aF[i] = *(const bf16x8*)(lds + bas + aOff + 4096 + i * 1024);
    if (T + 1 < NT) stageB(oth + 49152, kT + 96);  // B-kh1(T+1)
    if (T == NT - 1) asm volatile("s_waitcnt vmcnt(0)" ::: "memory");
    else             asm volatile("s_waitcnt vmcnt(8)" ::: "memory");
    __builtin_amdgcn_s_barrier();
    __builtin_amdgcn_s_setprio(1);
#pragma unroll
    for (int i = 0; i < 4; ++i)
#pragma unroll
      for (int j = 0; j < 4; ++j)
        acc[4 + i][j] = __builtin_amdgcn_mfma_f32_16x16x32_bf16(aF[i], bF[j], acc[4 + i][j], 0, 0, 0);
    __builtin_amdgcn_s_setprio(0);
    __builtin_amdgcn_s_barrier();

    // ---- q2: ks1, i-half0 ----
#pragma unroll
    for (int i = 0; i < 4; ++i) aF[i] = *(const bf16x8*)(lds + bas + 16384 + aOff + i * 1024);
#pragma unroll
    for (int j = 0; j < 4; ++j) bF[j] = *(const bf16x8*)(lds + bas + 49152 + bOff + j * 1024);
    if (T + 2 < NT) stageA(bas, kT + 128);  // A-kh0(T+2)
    __builtin_amdgcn_s_barrier();
    __builtin_amdgcn_s_setprio(1);
#pragma unroll
    for (int i = 0; i < 4; ++i)
#pragma unroll
      for (int j = 0; j < 4; ++j)
        acc[i][j] = __builtin_amdgcn_mfma_f32_16x16x32_bf16(aF[i], bF[j], acc[i][j], 0, 0, 0);
    __builtin_amdgcn_s_setprio(0);
    __builtin_amdgcn_s_barrier();

    // ---- q3: ks1, i-half1 ----
#pragma unroll
    for (int i = 0; i < 4; ++i) aF[i] = *(const bf16x8*)(lds + bas + 16384 + aOff + 4096 + i * 1024);
    if (T + 2 < NT) stageB(bas + 32768, kT + 128);  // B-kh0(T+2)
    if (T + 2 < NT)      asm volatile("s_waitcnt vmcnt(8)" ::: "memory");
    else if (T + 1 < NT) asm volatile("s_waitcnt vmcnt(4)" ::: "memory");
    __builtin_amdgcn_s_barrier();
    __builtin_amdgcn_s_setprio(1);
#pragma unroll
    for (int i = 0; i < 4; ++i)
#pragma unroll
      for (int j = 0; j < 4; ++j)
        acc[4 + i][j] = __builtin_amdgcn_mfma_f32_16x16x32_bf16(aF[i], bF[j], acc[4 + i][j], 0, 0, 0);
    __builtin_amdgcn_s_setprio(0);
    __builtin_amdgcn_s_barrier();
  }

  // C/D layout: col = lane&15 (N), row = (lane>>4)*4 + reg (M within 16)
  const int cmB = wm * 128 + ((lane >> 4) << 2);
  const int cn = n0 + wn * 64 + (lane & 15);
  if (MODE == 0) {
#pragma unroll
    for (int i = 0; i < 8; ++i)
#pragma unroll
      for (int r = 0; r < 4; ++r) {
        const int m = m0 + cmB + i * 16 + r;
        float rs = 0.f;
#pragma unroll
        for (int j = 0; j < 4; ++j) {
          const float e = __expf(fminf(acc[i][j][r] * 0.03125f, 30.0f));
          rs += e;
          Cb[(size_t)m * NS + cn + j * 16] = (__bf16)e;
        }
        rs += __shfl_xor(rs, 1, 64);
        rs += __shfl_xor(rs, 2, 64);
        rs += __shfl_xor(rs, 4, 64);
        rs += __shfl_xor(rs, 8, 64);
        if ((lane & 15) == 0) atomicAdd(&lsum[m], rs);
      }
  } else {
#pragma unroll
    for (int i = 0; i < 8; ++i)
#pragma unroll
      for (int r = 0; r < 4; ++r) {
        const int m = m0 + cmB + i * 16 + r;
        const float inv = 1.0f / lsum[m];
#pragma unroll
        for (int j = 0; j < 4; ++j)
          atomicAdd(&Cf[(size_t)m * NS + cn + j * 16], acc[i][j][r] * inv);
      }
  }
}

extern "C" void kernel_launch(void* const* d_in, const int* in_sizes, int n_in,
                              void* d_out, int out_size, void* d_ws, size_t ws_size,
                              hipStream_t stream) {
  const float* x = (const float*)d_in[0];  // [8192][1024] fp32
  const float* K = (const float*)d_in[1];  // [4096][1024] fp32
  const float* V = (const float*)d_in[2];  // [4096][1024] fp32
  float* out = (float*)d_out;              // [8192][1024] fp32

  char* ws = (char*)d_ws;
  __bf16* xb = (__bf16*)ws;                        // 16 MiB
  __bf16* Kb = (__bf16*)(ws + (16u << 20));        // 8 MiB
  __bf16* Vt = (__bf16*)(ws + (24u << 20));        // 8 MiB
  __bf16* P  = (__bf16*)(ws + (32u << 20));        // 64 MiB
  float*  l  = (float*)(ws + (96u << 20));         // 32 KiB

  preprocess_kernel<<<6145, 256, 0, stream>>>(x, K, V, xb, Kb, Vt, l, out);
  // P = exp(xb @ Kb^T / 32), fused row sums (M=8192 N=4096 K=1024), 512 blocks
  gemm_kernel<0, 1024, 1024, 4096, 4, 1><<<512, 512, 0, stream>>>(xb, Kb, P, nullptr, l);
  // out += (P @ Vt-rows)/l, K-split=2 (M=8192 N=1024 K=2x2048), 256 blocks
  gemm_kernel<1, 4096, 2048, 1024, 4, 2><<<256, 512, 0, stream>>>(P, Vt, nullptr, out, l);
}